// Round 16
// baseline (134.444 us; speedup 1.0000x reference)
//
#include <hip/hip_runtime.h>
#include <stdint.h>

typedef uint32_t u32;
typedef unsigned long long u64;
typedef unsigned short ushort;
typedef __attribute__((ext_vector_type(8))) short short8;
typedef __attribute__((ext_vector_type(4))) float f32x4;

#define NPTS 65536
#define HEADS 8
#define DIM 32
#define HD 256          // HEADS*DIM
#define BSZ 128         // LSH block size
#define NBLK 512        // NPTS/BSZ
#define SCALE_QK 0.17677669529663687f   // 1/sqrt(32)
#define LOG2E 1.4426950408889634f

// ======================= JAX RNG replication =======================
__device__ __forceinline__ u32 rotl32(u32 v, int r){ return (v << r) | (v >> (32 - r)); }

__device__ void threefry2x32_0_42(u32 x0, u32 x1, u32& o0, u32& o1){
  const u32 ks0 = 0u, ks1 = 42u;
  const u32 ks2 = ks0 ^ ks1 ^ 0x1BD11BDAu;
  x0 += ks0; x1 += ks1;
#define TF_RND(r) { x0 += x1; x1 = rotl32(x1, (r)); x1 ^= x0; }
  TF_RND(13) TF_RND(15) TF_RND(26) TF_RND(6)
  x0 += ks1; x1 += ks2 + 1u;
  TF_RND(17) TF_RND(29) TF_RND(16) TF_RND(24)
  x0 += ks2; x1 += ks0 + 2u;
  TF_RND(13) TF_RND(15) TF_RND(26) TF_RND(6)
  x0 += ks0; x1 += ks1 + 3u;
  TF_RND(17) TF_RND(29) TF_RND(16) TF_RND(24)
  x0 += ks1; x1 += ks2 + 4u;
  TF_RND(13) TF_RND(15) TF_RND(26) TF_RND(6)
  x0 += ks2; x1 += ks0 + 5u;
#undef TF_RND
  o0 = x0; o1 = x1;
}

__device__ float erfinv_xla_f32(float x){
  float w = -log1pf(-x * x);
  float p;
  if (w < 5.0f){
    w = w - 2.5f;
    p =            2.81022636e-08f;
    p = fmaf(p, w, 3.43273939e-07f);
    p = fmaf(p, w, -3.5233877e-06f);
    p = fmaf(p, w, -4.39150654e-06f);
    p = fmaf(p, w,  0.00021858087f);
    p = fmaf(p, w, -0.00125372503f);
    p = fmaf(p, w, -0.00417768164f);
    p = fmaf(p, w,  0.246640727f);
    p = fmaf(p, w,  1.50140941f);
  } else {
    w = sqrtf(w) - 3.0f;
    p =            -0.000200214257f;
    p = fmaf(p, w,  0.000100950558f);
    p = fmaf(p, w,  0.00134934322f);
    p = fmaf(p, w, -0.00367342844f);
    p = fmaf(p, w,  0.00573950773f);
    p = fmaf(p, w, -0.0076224613f);
    p = fmaf(p, w,  0.00943887047f);
    p = fmaf(p, w,  1.00167406f);
    p = fmaf(p, w,  2.83297682f);
  }
  return p * x;
}

__device__ float jax_normal_from_bits(u32 bits){
  float f = __uint_as_float((bits >> 9) | 0x3f800000u) - 1.0f;   // [0,1)
  const float mn = -0.99999994f;
  float v = fmaf(f, 2.0f, mn);
  v = fmaxf(mn, v);
  return 1.41421356237309505f * erfinv_xla_f32(v);
}

__device__ __forceinline__ ushort f2bf(float f){
  union { __bf16 b; ushort u; } cv;
  cv.b = (__bf16)f;
  return cv.u;
}

// ======================= sort: codes + 1024-bitonic + LN(x)->xn + W-prep + omega =======================
__global__ __launch_bounds__(512) void k_sort1024(const float* __restrict__ coords,
                                                  const float* __restrict__ Wrpe,
                                                  const float* __restrict__ x,
                                                  const float* __restrict__ g1,
                                                  const float* __restrict__ be1,
                                                  const float* __restrict__ Wq,
                                                  const float* __restrict__ Wk,
                                                  const float* __restrict__ Wv,
                                                  float* __restrict__ omega,
                                                  ushort* __restrict__ xn,
                                                  ushort* __restrict__ wbf,
                                                  u64* __restrict__ A0, u64* __restrict__ A1){
  __shared__ u64 sh[1024];
  int t = threadIdx.x;
  int bb = blockIdx.x;
  int r = (bb >= 64);
  u64* A = r ? A1 : A0;
  int base = (bb & 63) * 1024;
  int gt = bb*512 + t;

  // ---- LN of x row gt -> xn bf16 ----
  {
    const float4* xp = (const float4*)(x + (size_t)gt*32);
    float mu = 0.f, s2 = 0.f;
    #pragma unroll
    for (int c4 = 0; c4 < 8; c4++){
      float4 f = xp[c4];
      mu += f.x + f.y + f.z + f.w;
      s2 = fmaf(f.x,f.x, fmaf(f.y,f.y, fmaf(f.z,f.z, fmaf(f.w,f.w, s2))));
    }
    mu *= (1.0f/32.0f);
    float var = fmaf(-mu, mu, s2*(1.0f/32.0f));
    float rs = rsqrtf(var + 1e-5f);
    #pragma unroll
    for (int c4 = 0; c4 < 8; c4++){
      float4 f = xp[c4];
      u32 w0 = (u32)f2bf((f.x-mu)*rs*g1[c4*4+0] + be1[c4*4+0])
             | ((u32)f2bf((f.y-mu)*rs*g1[c4*4+1] + be1[c4*4+1]) << 16);
      u32 w1 = (u32)f2bf((f.z-mu)*rs*g1[c4*4+2] + be1[c4*4+2])
             | ((u32)f2bf((f.w-mu)*rs*g1[c4*4+3] + be1[c4*4+3]) << 16);
      *(uint2*)&xn[(size_t)gt*32 + c4*4] = make_uint2(w0, w1);
    }
  }

  // ---- W-prep: one bf16 element per thread (gt < 8*96*32) ----
  if (gt < 24576){
    int c = gt & 31;
    int rh = gt >> 5;           // h*96 + row96
    int h = rh / 96;
    int row96 = rh - h*96;
    int m = row96 >> 5, dl = row96 & 31;
    const float* Wm = (m == 0) ? Wq : (m == 1) ? Wk : Wv;
    float v = Wm[c*HD + h*32 + dl];
    if (m == 0) v *= SCALE_QK * LOG2E;
    wbf[gt] = f2bf(v);          // wbf[h*3072 + row96*32 + c]
  }

  // ---- codes + keys + bitonic(1024) ----
  float pr[3];
  #pragma unroll
  for (int j = 0; j < 3; j++){
    u32 a, b;
    threefry2x32_0_42((u32)j, (u32)(j + 3), a, b);
    pr[j] = jax_normal_from_bits(r ? b : a);
  }
  #pragma unroll
  for (int half = 0; half < 2; half++){
    int idx = base + t + half*512;
    float c0 = coords[idx*3+0], c1 = coords[idx*3+1], c2 = coords[idx*3+2];
    float code = fmaf(c2, pr[2], fmaf(c1, pr[1], c0*pr[0]));
    u32 u = __float_as_uint(code);
    u32 key = (u & 0x80000000u) ? ~u : (u | 0x80000000u);
    sh[t + half*512] = ((u64)key << 32) | (u64)(u32)idx;
  }
  __syncthreads();
  for (int k = 2; k <= 1024; k <<= 1){
    for (int j = k >> 1; j > 0; j >>= 1){
      int idx = ((t & ~(j-1)) << 1) | (t & (j-1));
      int par = idx | j;
      bool up = ((idx & k) == 0);
      u64 a = sh[idx], b = sh[par];
      if ((a > b) == up){ sh[idx] = b; sh[par] = a; }
      __syncthreads();
    }
  }
  A[base + t] = sh[t];
  A[base + t + 512] = sh[t + 512];

  if (bb == 0 && t < 16){
    int h = t >> 1, rr = t & 1;
    float s = 0.f;
    for (int wi = 0; wi < 3; wi++)
      for (int d = 0; d < 32; d++){
        float w = Wrpe[(rr*3 + wi)*HD + h*32 + d];
        s = fmaf(w, w, s);
      }
    omega[t] = s * (1.0f/96.0f);
  }
}

// ======================= multi-run merge =======================
template<int NRG>
__global__ void k_merge2(const u64* __restrict__ s0, const u64* __restrict__ s1,
                         u64* __restrict__ d0, u64* __restrict__ d1, int lgL){
  int gb = blockIdx.x;
  const u64* src = (gb < 256) ? s0 : s1;
  u64*       dst = (gb < 256) ? d0 : d1;
  int g = (gb & 255) * 256 + threadIdx.x;
  int L = 1 << lgL;
  u64 e = src[g];
  int myrun = (g >> lgL) & (NRG - 1);
  int gbase = g & ~(NRG*L - 1);
  int pos = g & (L - 1);
  #pragma unroll
  for (int o = 0; o < NRG; o++){
    if (o == myrun) continue;
    const u64* run = src + gbase + o*L;
    int lo = 0, hi = L;
    while (lo < hi){
      int mid = (lo + hi) >> 1;
      if (run[mid] < e) lo = mid + 1; else hi = mid;
    }
    pos += lo;
  }
  dst[gbase + pos] = e;
}

// ======================= attention (all-MFMA, precomputed aug tables) =======================
// grid 8192: h = bid>>10, b = (bid>>1)&511, r = bid&1 (XCD-locality).
// Phase 1: t<128 copies xn row -> Xs AND builds augK/augQ bf16 tables; t>=128 copies wbf[h].
// Phase 2: Q,K swapped-operand MFMA -> uint2 wb; V -> Vt[d][key].
// Phase 3: S^T = mfma(A=K, B=Q^T) + aug (masked b64 table reads); exp2; P; O^T; uint2 out.
__global__ __launch_bounds__(256, 4) void k_attn(const u64* __restrict__ s0,
    const u64* __restrict__ s1,
    const ushort* __restrict__ xn, const float* __restrict__ coords,
    const ushort* __restrict__ wbf,
    const float* __restrict__ omega, ushort* __restrict__ ag0, ushort* __restrict__ ag1){
  __shared__ __align__(16) char smem[39424];
  ushort* Xs = (ushort*)(smem + 0);        // [128][40]  (phase 1-2; Qs overlays)
  ushort* Wt = (ushort*)(smem + 10240);    // [96][40]   (phase 1-2)
  ushort* Ps = (ushort*)(smem + 0);        // [4][16][136] aliases Xs/Wt (phase 3 tail)
  ushort* Ks = (ushort*)(smem + 17920);    // [128][40]
  ushort* Vt = (ushort*)(smem + 28160);    // [32][136]
  int*    gq_s = (int*)(smem + 36864);     // [128]
  ushort* augK = (ushort*)(smem + 37376);  // [128][4] bf16 {px, py, nK, 0}
  ushort* augQ = (ushort*)(smem + 38400);  // [128][4] bf16 {cx, cy, 1, 0}
  ushort* Qs = Xs;                         // Q writeback target (rows wave-private)

  const int bid = blockIdx.x;
  const int h = bid >> 10;
  const int b = (bid >> 1) & 511;
  const int r = bid & 1;
  const u64* sorted = r ? s1 : s0;
  ushort* aggr = r ? ag1 : ag0;

  const int t = threadIdx.x;
  const int w = t >> 6, l = t & 63, lg = l >> 4, lc = l & 15;
  const int R = w * 32;

  // ---------- phase 1: staging ----------
  if (t < 128){
    int gp = (int)(u32)(sorted[b*BSZ + t] & 0xffffffffull);
    gq_s[t] = gp;
    float px = coords[gp*3+0], py = coords[gp*3+1];
    float om0 = omega[h*2+0] * LOG2E, om1 = omega[h*2+1] * LOG2E;  // scalar (uniform)
    float nK = -fmaf(om0, px*px, om1*(py*py));
    *(uint2*)&augK[t*4] = make_uint2((u32)f2bf(px) | ((u32)f2bf(py) << 16), (u32)f2bf(nK));
    *(uint2*)&augQ[t*4] = make_uint2((u32)f2bf(2.0f*om0*px) | ((u32)f2bf(2.0f*om1*py) << 16),
                                     (u32)f2bf(1.0f));
    const uint4* xr = (const uint4*)(xn + (size_t)gp*32);
    #pragma unroll
    for (int q4 = 0; q4 < 4; q4++)
      *(uint4*)&Xs[t*40 + q4*8] = xr[q4];
  } else {
    int tt = t - 128;                       // 0..127
    const ushort* wsrc = wbf + h*3072;
    #pragma unroll
    for (int e = 0; e < 3; e++){
      int idx = tt + e*128;
      int row = idx >> 2, c4 = idx & 3;
      *(uint4*)&Wt[row*40 + c4*8] = *(const uint4*)&wsrc[idx*8];
    }
  }
  __syncthreads();

  // ---------- phase 2: QKV via MFMA, all-uint2 writebacks ----------
  {
    short8 a0 = *(const short8*)&Xs[(R      + lc)*40 + lg*8];
    short8 a1 = *(const short8*)&Xs[(R + 16 + lc)*40 + lg*8];
    const f32x4 z = (f32x4){0.f,0.f,0.f,0.f};
    #pragma unroll
    for (int dt = 0; dt < 2; dt++){
      short8 wq = *(const short8*)&Wt[(     dt*16 + lc)*40 + lg*8];
      short8 wk = *(const short8*)&Wt[(32 + dt*16 + lc)*40 + lg*8];
      f32x4 q0 = __builtin_amdgcn_mfma_f32_16x16x32_bf16(wq, a0, z, 0, 0, 0);
      f32x4 q1 = __builtin_amdgcn_mfma_f32_16x16x32_bf16(wq, a1, z, 0, 0, 0);
      f32x4 k0 = __builtin_amdgcn_mfma_f32_16x16x32_bf16(wk, a0, z, 0, 0, 0);
      f32x4 k1 = __builtin_amdgcn_mfma_f32_16x16x32_bf16(wk, a1, z, 0, 0, 0);
      u32 qw0 = (u32)f2bf(q0[0]) | ((u32)f2bf(q0[1]) << 16);
      u32 qw1 = (u32)f2bf(q0[2]) | ((u32)f2bf(q0[3]) << 16);
      *(uint2*)&Qs[(R      + lc)*40 + dt*16 + lg*4] = make_uint2(qw0, qw1);
      qw0 = (u32)f2bf(q1[0]) | ((u32)f2bf(q1[1]) << 16);
      qw1 = (u32)f2bf(q1[2]) | ((u32)f2bf(q1[3]) << 16);
      *(uint2*)&Qs[(R + 16 + lc)*40 + dt*16 + lg*4] = make_uint2(qw0, qw1);
      u32 kw0 = (u32)f2bf(k0[0]) | ((u32)f2bf(k0[1]) << 16);
      u32 kw1 = (u32)f2bf(k0[2]) | ((u32)f2bf(k0[3]) << 16);
      *(uint2*)&Ks[(R      + lc)*40 + dt*16 + lg*4] = make_uint2(kw0, kw1);
      kw0 = (u32)f2bf(k1[0]) | ((u32)f2bf(k1[1]) << 16);
      kw1 = (u32)f2bf(k1[2]) | ((u32)f2bf(k1[3]) << 16);
      *(uint2*)&Ks[(R + 16 + lc)*40 + dt*16 + lg*4] = make_uint2(kw0, kw1);
    }
    #pragma unroll
    for (int vt = 0; vt < 2; vt++){
      short8 wv = *(const short8*)&Wt[(64 + vt*16 + lc)*40 + lg*8];
      f32x4 v0 = __builtin_amdgcn_mfma_f32_16x16x32_bf16(a0, wv, z, 0, 0, 0);
      f32x4 v1 = __builtin_amdgcn_mfma_f32_16x16x32_bf16(a1, wv, z, 0, 0, 0);
      u32 vw0 = (u32)f2bf(v0[0]) | ((u32)f2bf(v0[1]) << 16);
      u32 vw1 = (u32)f2bf(v0[2]) | ((u32)f2bf(v0[3]) << 16);
      *(uint2*)&Vt[(vt*16 + lc)*136 + R      + lg*4] = make_uint2(vw0, vw1);
      vw0 = (u32)f2bf(v1[0]) | ((u32)f2bf(v1[1]) << 16);
      vw1 = (u32)f2bf(v1[2]) | ((u32)f2bf(v1[3]) << 16);
      *(uint2*)&Vt[(vt*16 + lc)*136 + R + 16 + lg*4] = make_uint2(vw0, vw1);
    }
  }
  __syncthreads();

  // ---------- phase 3 ----------
  short8 bq[2];
  bq[0] = *(const short8*)&Qs[(R      + lc)*40 + lg*8];
  bq[1] = *(const short8*)&Qs[(R + 16 + lc)*40 + lg*8];

  // aug B-frags from precomputed table (masked b64 read)
  short8 bAug[2];
  #pragma unroll
  for (int qt = 0; qt < 2; qt++){
    uint2 ra = (lg == 0) ? *(const uint2*)&augQ[(R + qt*16 + lc)*4] : make_uint2(0u, 0u);
    u32 wrd[4] = {ra.x, ra.y, 0u, 0u};
    bAug[qt] = *(short8*)&wrd[0];
  }

  f32x4 acc[2][8];
  #pragma unroll
  for (int kt = 0; kt < 8; kt++){
    short8 ak = *(const short8*)&Ks[(kt*16 + lc)*40 + lg*8];
    uint2 rk = (lg == 0) ? *(const uint2*)&augK[(kt*16 + lc)*4] : make_uint2(0u, 0u);
    u32 wrd[4] = {rk.x, rk.y, 0u, 0u};
    short8 aAug = *(short8*)&wrd[0];
    acc[0][kt] = __builtin_amdgcn_mfma_f32_16x16x32_bf16(ak, bq[0], (f32x4){0.f,0.f,0.f,0.f}, 0, 0, 0);
    acc[1][kt] = __builtin_amdgcn_mfma_f32_16x16x32_bf16(ak, bq[1], (f32x4){0.f,0.f,0.f,0.f}, 0, 0, 0);
    acc[0][kt] = __builtin_amdgcn_mfma_f32_16x16x32_bf16(aAug, bAug[0], acc[0][kt], 0, 0, 0);
    acc[1][kt] = __builtin_amdgcn_mfma_f32_16x16x32_bf16(aAug, bAug[1], acc[1][kt], 0, 0, 0);
  }

  float lr[2] = {0.f, 0.f};
  #pragma unroll
  for (int qt = 0; qt < 2; qt++)
    #pragma unroll
    for (int kt = 0; kt < 8; kt++)
      #pragma unroll
      for (int i = 0; i < 4; i++){
        float e = exp2f(acc[qt][kt][i]);
        acc[qt][kt][i] = e;
        lr[qt] += e;
      }
  #pragma unroll
  for (int qt = 0; qt < 2; qt++){
    float s = lr[qt];
    s += __shfl_xor(s, 16);
    s += __shfl_xor(s, 32);
    lr[qt] = 0.5f / s;      // includes /NH; applied at output
  }

  short8 av[4][2];
  #pragma unroll
  for (int cc = 0; cc < 4; cc++)
    #pragma unroll
    for (int dt = 0; dt < 2; dt++)
      av[cc][dt] = *(const short8*)&Vt[(dt*16 + lc)*136 + cc*32 + lg*8];

  __syncthreads();   // all waves done reading Qs/Ks -> Ps may overwrite Xs/Wt

  ushort* Psw = Ps + w*16*136;
  f32x4 oT[2][2];
  #pragma unroll
  for (int dt = 0; dt < 2; dt++)
    #pragma unroll
    for (int qt = 0; qt < 2; qt++) oT[dt][qt] = (f32x4){0.f,0.f,0.f,0.f};

  #pragma unroll
  for (int qt = 0; qt < 2; qt++){
    asm volatile("s_waitcnt lgkmcnt(0)" ::: "memory");
    __builtin_amdgcn_sched_barrier(0);
    #pragma unroll
    for (int kt = 0; kt < 8; kt++){
      u32 p0 = (u32)f2bf(acc[qt][kt][0]) | ((u32)f2bf(acc[qt][kt][1]) << 16);
      u32 p1 = (u32)f2bf(acc[qt][kt][2]) | ((u32)f2bf(acc[qt][kt][3]) << 16);
      *(uint2*)&Psw[lc*136 + kt*16 + lg*4] = make_uint2(p0, p1);
    }
    asm volatile("s_waitcnt lgkmcnt(0)" ::: "memory");
    __builtin_amdgcn_sched_barrier(0);
    __builtin_amdgcn_s_setprio(1);
    #pragma unroll
    for (int cc = 0; cc < 4; cc++){
      short8 bp = *(const short8*)&Psw[lc*136 + cc*32 + lg*8];
      oT[0][qt] = __builtin_amdgcn_mfma_f32_16x16x32_bf16(av[cc][0], bp, oT[0][qt], 0, 0, 0);
      oT[1][qt] = __builtin_amdgcn_mfma_f32_16x16x32_bf16(av[cc][1], bp, oT[1][qt], 0, 0, 0);
    }
    __builtin_amdgcn_s_setprio(0);
  }

  #pragma unroll
  for (int qt = 0; qt < 2; qt++){
    int g = gq_s[R + qt*16 + lc];
    float lrq = lr[qt];
    ushort* dst = aggr + (size_t)g*HD + h*32;
    #pragma unroll
    for (int dt = 0; dt < 2; dt++){
      u32 w0 = (u32)f2bf(oT[dt][qt][0]*lrq) | ((u32)f2bf(oT[dt][qt][1]*lrq) << 16);
      u32 w1 = (u32)f2bf(oT[dt][qt][2]*lrq) | ((u32)f2bf(oT[dt][qt][3]*lrq) << 16);
      *(uint2*)&dst[dt*16 + lg*4] = make_uint2(w0, w1);
    }
  }
}

// ======================= fused epilogue: Wo + residual + LN2 + FFN (all-MFMA) =======================
__global__ __launch_bounds__(256) void k_out(const float* __restrict__ x,
    const ushort* __restrict__ ag0, const ushort* __restrict__ ag1,
    const float* __restrict__ Wo, const float* __restrict__ bo,
    const float* __restrict__ g2, const float* __restrict__ be2,
    const float* __restrict__ W1, const float* __restrict__ b1,
    const float* __restrict__ W2, const float* __restrict__ b2,
    float* __restrict__ out){
  __shared__ ushort Wot[32*264];    // [col][k 0..255 +8]
  __shared__ ushort W1t[32*40];
  __shared__ ushort W2t[32*40];
  __shared__ ushort Bnc[4][16*40];
  int t = threadIdx.x;
  #pragma unroll
  for (int e = 0; e < 32; e++){
    int flat = t + e*256;
    int k = flat >> 5, col = flat & 31;
    Wot[col*264 + k] = f2bf(Wo[flat]);
  }
  #pragma unroll
  for (int e = 0; e < 4; e++){
    int flat = t + e*256;
    int k = flat >> 5, col = flat & 31;
    W1t[col*40 + k] = f2bf(W1[flat]);
    W2t[col*40 + k] = f2bf(W2[flat]);
  }
  __syncthreads();

  const int w = t >> 6, l = t & 63, lg = l >> 4, lc = l & 15;
  const int r0 = blockIdx.x*64 + w*16;

  f32x4 acc[2];
  acc[0] = (f32x4){0.f,0.f,0.f,0.f};
  acc[1] = (f32x4){0.f,0.f,0.f,0.f};
  #pragma unroll
  for (int ks = 0; ks < 8; ks++){
    short8 a0 = *(const short8*)(ag0 + (size_t)(r0+lc)*256 + ks*32 + lg*8);
    short8 a1 = *(const short8*)(ag1 + (size_t)(r0+lc)*256 + ks*32 + lg*8);
    #pragma unroll
    for (int ct = 0; ct < 2; ct++){
      short8 bb = *(const short8*)&Wot[(ct*16 + lc)*264 + ks*32 + lg*8];
      acc[ct] = __builtin_amdgcn_mfma_f32_16x16x32_bf16(a0, bb, acc[ct], 0, 0, 0);
      acc[ct] = __builtin_amdgcn_mfma_f32_16x16x32_bf16(a1, bb, acc[ct], 0, 0, 0);
    }
  }
  float x2v[2][4];
  #pragma unroll
  for (int ct = 0; ct < 2; ct++){
    int col = ct*16 + lc;
    float bov = bo[col];
    #pragma unroll
    for (int i = 0; i < 4; i++){
      int row = r0 + lg*4 + i;
      x2v[ct][i] = x[row*32 + col] + acc[ct][i] + bov;
    }
  }

  float g2v[2], be2v[2], b1v[2], b2v[2];
  #pragma unroll
  for (int ct = 0; ct < 2; ct++){
    int col = ct*16 + lc;
    g2v[ct] = g2[col]; be2v[ct] = be2[col]; b1v[ct] = b1[col]; b2v[ct] = b2[col];
  }
  ushort* B = &Bnc[w][0];
  #pragma unroll
  for (int i = 0; i < 4; i++){
    float m = x2v[0][i] + x2v[1][i];
    m += __shfl_xor(m, 1); m += __shfl_xor(m, 2);
    m += __shfl_xor(m, 4); m += __shfl_xor(m, 8);
    float mu = m * (1.0f/32.0f);
    float d0 = x2v[0][i] - mu, d1 = x2v[1][i] - mu;
    float v = fmaf(d0, d0, d1*d1);
    v += __shfl_xor(v, 1); v += __shfl_xor(v, 2);
    v += __shfl_xor(v, 4); v += __shfl_xor(v, 8);
    float rs = rsqrtf(v * (1.0f/32.0f) + 1e-5f);
    B[(lg*4 + i)*40 +      lc] = f2bf(d0 * rs * g2v[0] + be2v[0]);
    B[(lg*4 + i)*40 + 16 + lc] = f2bf(d1 * rs * g2v[1] + be2v[1]);
  }
  asm volatile("s_waitcnt lgkmcnt(0)" ::: "memory");
  __builtin_amdgcn_sched_barrier(0);

  short8 ha = *(const short8*)&B[lc*40 + lg*8];
  f32x4 f1[2];
  #pragma unroll
  for (int ct = 0; ct < 2; ct++){
    short8 bb = *(const short8*)&W1t[(ct*16 + lc)*40 + lg*8];
    f1[ct] = __builtin_amdgcn_mfma_f32_16x16x32_bf16(ha, bb, (f32x4){0.f,0.f,0.f,0.f}, 0, 0, 0);
  }
  asm volatile("s_waitcnt lgkmcnt(0)" ::: "memory");
  __builtin_amdgcn_sched_barrier(0);
  #pragma unroll
  for (int ct = 0; ct < 2; ct++)
    #pragma unroll
    for (int i = 0; i < 4; i++)
      B[(lg*4 + i)*40 + ct*16 + lc] = f2bf(fmaxf(f1[ct][i] + b1v[ct], 0.f));
  asm volatile("s_waitcnt lgkmcnt(0)" ::: "memory");
  __builtin_amdgcn_sched_barrier(0);

  short8 ta = *(const short8*)&B[lc*40 + lg*8];
  #pragma unroll
  for (int ct = 0; ct < 2; ct++){
    short8 bb = *(const short8*)&W2t[(ct*16 + lc)*40 + lg*8];
    f32x4 f2 = __builtin_amdgcn_mfma_f32_16x16x32_bf16(ta, bb, (f32x4){0.f,0.f,0.f,0.f}, 0, 0, 0);
    int col = ct*16 + lc;
    #pragma unroll
    for (int i = 0; i < 4; i++){
      int row = r0 + lg*4 + i;
      out[row*32 + col] = x2v[ct][i] + f2[i] + b2v[ct];
    }
  }
}

// ======================= launch =======================
extern "C" void kernel_launch(void* const* d_in, const int* in_sizes, int n_in,
                              void* d_out, int out_size, void* d_ws, size_t ws_size,
                              hipStream_t stream) {
  (void)in_sizes; (void)n_in; (void)out_size; (void)ws_size;
  const float* x      = (const float*)d_in[0];
  const float* coords = (const float*)d_in[1];
  const float* g1     = (const float*)d_in[2];
  const float* be1    = (const float*)d_in[3];
  const float* Wq     = (const float*)d_in[4];
  const float* Wk     = (const float*)d_in[5];
  const float* Wv     = (const float*)d_in[6];
  const float* Wrpe   = (const float*)d_in[7];
  const float* Wo     = (const float*)d_in[8];
  const float* bo     = (const float*)d_in[9];
  const float* g2     = (const float*)d_in[10];
  const float* be2    = (const float*)d_in[11];
  const float* W1     = (const float*)d_in[12];
  const float* b1     = (const float*)d_in[13];
  const float* W2     = (const float*)d_in[14];
  const float* b2     = (const float*)d_in[15];
  float* out = (float*)d_out;

  char* ws = (char*)d_ws;
  ushort* ag0   = (ushort*)(ws + 0);           // 32 MB bf16 (NPTS*HD)
  ushort* ag1   = (ushort*)(ws + 33554432);    // 32 MB
  ushort* xn    = (ushort*)(ws + 67108864);    // 4 MB bf16 (NPTS*32)
  u64*   keyA0  = (u64*)  (ws + 71303168);     // 512 KB
  u64*   keyA1  = (u64*)  (ws + 71827456);     // 512 KB
  u64*   keyB0  = (u64*)  (ws + 72351744);     // 512 KB
  u64*   keyB1  = (u64*)  (ws + 72876032);     // 512 KB
  float* omega  = (float*)(ws + 73400320);     // 64 B
  ushort* wbf   = (ushort*)(ws + 73400448);    // 48 KB bf16

  k_sort1024<<<128, 512, 0, stream>>>(coords, Wrpe, x, g1, be1, Wq, Wk, Wv,
                                      omega, xn, wbf, keyA0, keyA1);
  // 3 merge passes: 1024 -> 4096 -> 16384 -> 65536  (A->B->A->B)
  k_merge2<4><<<512, 256, 0, stream>>>(keyA0, keyA1, keyB0, keyB1, 10);
  k_merge2<4><<<512, 256, 0, stream>>>(keyB0, keyB1, keyA0, keyA1, 12);
  k_merge2<4><<<512, 256, 0, stream>>>(keyA0, keyA1, keyB0, keyB1, 14);

  // both LSH rounds in one dispatch (separate output buffers)
  k_attn<<<NBLK*HEADS*2, 256, 0, stream>>>(keyB0, keyB1, xn, coords, wbf,
                                           omega, ag0, ag1);

  // fused Wo + residual + LN2 + FFN + residual
  k_out<<<NPTS/64, 256, 0, stream>>>(x, ag0, ag1, Wo, bo, g2, be2, W1, b1, W2, b2, out);
}

// Round 17
// 132.653 us; speedup vs baseline: 1.0135x; 1.0135x over previous
//
#include <hip/hip_runtime.h>
#include <stdint.h>

typedef uint32_t u32;
typedef unsigned long long u64;
typedef unsigned short ushort;
typedef __attribute__((ext_vector_type(8))) short short8;
typedef __attribute__((ext_vector_type(4))) float f32x4;

#define NPTS 65536
#define HEADS 8
#define DIM 32
#define HD 256          // HEADS*DIM
#define BSZ 128         // LSH block size
#define NBLK 512        // NPTS/BSZ
#define SCALE_QK 0.17677669529663687f   // 1/sqrt(32)
#define LOG2E 1.4426950408889634f

// ======================= JAX RNG replication =======================
__device__ __forceinline__ u32 rotl32(u32 v, int r){ return (v << r) | (v >> (32 - r)); }

__device__ void threefry2x32_0_42(u32 x0, u32 x1, u32& o0, u32& o1){
  const u32 ks0 = 0u, ks1 = 42u;
  const u32 ks2 = ks0 ^ ks1 ^ 0x1BD11BDAu;
  x0 += ks0; x1 += ks1;
#define TF_RND(r) { x0 += x1; x1 = rotl32(x1, (r)); x1 ^= x0; }
  TF_RND(13) TF_RND(15) TF_RND(26) TF_RND(6)
  x0 += ks1; x1 += ks2 + 1u;
  TF_RND(17) TF_RND(29) TF_RND(16) TF_RND(24)
  x0 += ks2; x1 += ks0 + 2u;
  TF_RND(13) TF_RND(15) TF_RND(26) TF_RND(6)
  x0 += ks0; x1 += ks1 + 3u;
  TF_RND(17) TF_RND(29) TF_RND(16) TF_RND(24)
  x0 += ks1; x1 += ks2 + 4u;
  TF_RND(13) TF_RND(15) TF_RND(26) TF_RND(6)
  x0 += ks2; x1 += ks0 + 5u;
#undef TF_RND
  o0 = x0; o1 = x1;
}

__device__ float erfinv_xla_f32(float x){
  float w = -log1pf(-x * x);
  float p;
  if (w < 5.0f){
    w = w - 2.5f;
    p =            2.81022636e-08f;
    p = fmaf(p, w, 3.43273939e-07f);
    p = fmaf(p, w, -3.5233877e-06f);
    p = fmaf(p, w, -4.39150654e-06f);
    p = fmaf(p, w,  0.00021858087f);
    p = fmaf(p, w, -0.00125372503f);
    p = fmaf(p, w, -0.00417768164f);
    p = fmaf(p, w,  0.246640727f);
    p = fmaf(p, w,  1.50140941f);
  } else {
    w = sqrtf(w) - 3.0f;
    p =            -0.000200214257f;
    p = fmaf(p, w,  0.000100950558f);
    p = fmaf(p, w,  0.00134934322f);
    p = fmaf(p, w, -0.00367342844f);
    p = fmaf(p, w,  0.00573950773f);
    p = fmaf(p, w, -0.0076224613f);
    p = fmaf(p, w,  0.00943887047f);
    p = fmaf(p, w,  1.00167406f);
    p = fmaf(p, w,  2.83297682f);
  }
  return p * x;
}

__device__ float jax_normal_from_bits(u32 bits){
  float f = __uint_as_float((bits >> 9) | 0x3f800000u) - 1.0f;   // [0,1)
  const float mn = -0.99999994f;
  float v = fmaf(f, 2.0f, mn);
  v = fmaxf(mn, v);
  return 1.41421356237309505f * erfinv_xla_f32(v);
}

__device__ __forceinline__ ushort f2bf(float f){
  union { __bf16 b; ushort u; } cv;
  cv.b = (__bf16)f;
  return cv.u;
}

// ======================= sort: codes + 1024-bitonic + LN(x)->xn + W-prep + omega =======================
__global__ __launch_bounds__(512) void k_sort1024(const float* __restrict__ coords,
                                                  const float* __restrict__ Wrpe,
                                                  const float* __restrict__ x,
                                                  const float* __restrict__ g1,
                                                  const float* __restrict__ be1,
                                                  const float* __restrict__ Wq,
                                                  const float* __restrict__ Wk,
                                                  const float* __restrict__ Wv,
                                                  float* __restrict__ omega,
                                                  ushort* __restrict__ xn,
                                                  ushort* __restrict__ wbf,
                                                  u64* __restrict__ A0, u64* __restrict__ A1){
  __shared__ u64 sh[1024];
  int t = threadIdx.x;
  int bb = blockIdx.x;
  int r = (bb >= 64);
  u64* A = r ? A1 : A0;
  int base = (bb & 63) * 1024;
  int gt = bb*512 + t;

  // ---- LN of x row gt -> xn bf16 ----
  {
    const float4* xp = (const float4*)(x + (size_t)gt*32);
    float mu = 0.f, s2 = 0.f;
    #pragma unroll
    for (int c4 = 0; c4 < 8; c4++){
      float4 f = xp[c4];
      mu += f.x + f.y + f.z + f.w;
      s2 = fmaf(f.x,f.x, fmaf(f.y,f.y, fmaf(f.z,f.z, fmaf(f.w,f.w, s2))));
    }
    mu *= (1.0f/32.0f);
    float var = fmaf(-mu, mu, s2*(1.0f/32.0f));
    float rs = rsqrtf(var + 1e-5f);
    #pragma unroll
    for (int c4 = 0; c4 < 8; c4++){
      float4 f = xp[c4];
      u32 w0 = (u32)f2bf((f.x-mu)*rs*g1[c4*4+0] + be1[c4*4+0])
             | ((u32)f2bf((f.y-mu)*rs*g1[c4*4+1] + be1[c4*4+1]) << 16);
      u32 w1 = (u32)f2bf((f.z-mu)*rs*g1[c4*4+2] + be1[c4*4+2])
             | ((u32)f2bf((f.w-mu)*rs*g1[c4*4+3] + be1[c4*4+3]) << 16);
      *(uint2*)&xn[(size_t)gt*32 + c4*4] = make_uint2(w0, w1);
    }
  }

  // ---- W-prep: one bf16 element per thread (gt < 8*96*32) ----
  if (gt < 24576){
    int c = gt & 31;
    int rh = gt >> 5;           // h*96 + row96
    int h = rh / 96;
    int row96 = rh - h*96;
    int m = row96 >> 5, dl = row96 & 31;
    const float* Wm = (m == 0) ? Wq : (m == 1) ? Wk : Wv;
    float v = Wm[c*HD + h*32 + dl];
    if (m == 0) v *= SCALE_QK * LOG2E;
    wbf[gt] = f2bf(v);          // wbf[h*3072 + row96*32 + c]
  }

  // ---- codes + keys + bitonic(1024) ----
  float pr[3];
  #pragma unroll
  for (int j = 0; j < 3; j++){
    u32 a, b;
    threefry2x32_0_42((u32)j, (u32)(j + 3), a, b);
    pr[j] = jax_normal_from_bits(r ? b : a);
  }
  #pragma unroll
  for (int half = 0; half < 2; half++){
    int idx = base + t + half*512;
    float c0 = coords[idx*3+0], c1 = coords[idx*3+1], c2 = coords[idx*3+2];
    float code = fmaf(c2, pr[2], fmaf(c1, pr[1], c0*pr[0]));
    u32 u = __float_as_uint(code);
    u32 key = (u & 0x80000000u) ? ~u : (u | 0x80000000u);
    sh[t + half*512] = ((u64)key << 32) | (u64)(u32)idx;
  }
  __syncthreads();
  for (int k = 2; k <= 1024; k <<= 1){
    for (int j = k >> 1; j > 0; j >>= 1){
      int idx = ((t & ~(j-1)) << 1) | (t & (j-1));
      int par = idx | j;
      bool up = ((idx & k) == 0);
      u64 a = sh[idx], b = sh[par];
      if ((a > b) == up){ sh[idx] = b; sh[par] = a; }
      __syncthreads();
    }
  }
  A[base + t] = sh[t];
  A[base + t + 512] = sh[t + 512];

  if (bb == 0 && t < 16){
    int h = t >> 1, rr = t & 1;
    float s = 0.f;
    for (int wi = 0; wi < 3; wi++)
      for (int d = 0; d < 32; d++){
        float w = Wrpe[(rr*3 + wi)*HD + h*32 + d];
        s = fmaf(w, w, s);
      }
    omega[t] = s * (1.0f/96.0f);
  }
}

// ======================= multi-run merge =======================
template<int NRG>
__global__ void k_merge2(const u64* __restrict__ s0, const u64* __restrict__ s1,
                         u64* __restrict__ d0, u64* __restrict__ d1, int lgL){
  int gb = blockIdx.x;
  const u64* src = (gb < 256) ? s0 : s1;
  u64*       dst = (gb < 256) ? d0 : d1;
  int g = (gb & 255) * 256 + threadIdx.x;
  int L = 1 << lgL;
  u64 e = src[g];
  int myrun = (g >> lgL) & (NRG - 1);
  int gbase = g & ~(NRG*L - 1);
  int pos = g & (L - 1);
  #pragma unroll
  for (int o = 0; o < NRG; o++){
    if (o == myrun) continue;
    const u64* run = src + gbase + o*L;
    int lo = 0, hi = L;
    while (lo < hi){
      int mid = (lo + hi) >> 1;
      if (run[mid] < e) lo = mid + 1; else hi = mid;
    }
    pos += lo;
  }
  dst[gbase + pos] = e;
}

// ======================= attention (all-MFMA, register-resident P) =======================
// grid 8192: h = bid>>10, b = (bid>>1)&511, r = bid&1 (XCD-locality).
// Phase 3 PV uses contraction-axis permutation invariance: P B-frag comes straight from
// the lane's own S^T accumulators (slot (lg,j) = key 32cc+(j>>2)*16+lg*4+(j&3)), and the
// V^T A-frag reads the SAME permuted key order from Vt (2x uint2 per frag). No P LDS.
__global__ __launch_bounds__(256, 4) void k_attn(const u64* __restrict__ s0,
    const u64* __restrict__ s1,
    const ushort* __restrict__ xn, const float* __restrict__ coords,
    const ushort* __restrict__ wbf,
    const float* __restrict__ omega, ushort* __restrict__ ag0, ushort* __restrict__ ag1){
  __shared__ __align__(16) char smem[39424];
  ushort* Xs = (ushort*)(smem + 0);        // [128][40]  (Qs overlays after phase 2)
  ushort* Wt = (ushort*)(smem + 10240);    // [96][40]
  ushort* Ks = (ushort*)(smem + 17920);    // [128][40]
  ushort* Vt = (ushort*)(smem + 28160);    // [32][136]
  int*    gq_s = (int*)(smem + 36864);     // [128]
  ushort* augK = (ushort*)(smem + 37376);  // [128][4] bf16 {px, py, nK, 0}
  ushort* augQ = (ushort*)(smem + 38400);  // [128][4] bf16 {cx, cy, 1, 0}
  ushort* Qs = Xs;                         // Q writeback target (rows wave-private)

  const int bid = blockIdx.x;
  const int h = bid >> 10;
  const int b = (bid >> 1) & 511;
  const int r = bid & 1;
  const u64* sorted = r ? s1 : s0;
  ushort* aggr = r ? ag1 : ag0;

  const int t = threadIdx.x;
  const int w = t >> 6, l = t & 63, lg = l >> 4, lc = l & 15;
  const int R = w * 32;
  (void)w;

  // ---------- phase 1: staging ----------
  if (t < 128){
    int gp = (int)(u32)(sorted[b*BSZ + t] & 0xffffffffull);
    gq_s[t] = gp;
    float px = coords[gp*3+0], py = coords[gp*3+1];
    float om0 = omega[h*2+0] * LOG2E, om1 = omega[h*2+1] * LOG2E;
    float nK = -fmaf(om0, px*px, om1*(py*py));
    *(uint2*)&augK[t*4] = make_uint2((u32)f2bf(px) | ((u32)f2bf(py) << 16), (u32)f2bf(nK));
    *(uint2*)&augQ[t*4] = make_uint2((u32)f2bf(2.0f*om0*px) | ((u32)f2bf(2.0f*om1*py) << 16),
                                     (u32)f2bf(1.0f));
    const uint4* xr = (const uint4*)(xn + (size_t)gp*32);
    #pragma unroll
    for (int q4 = 0; q4 < 4; q4++)
      *(uint4*)&Xs[t*40 + q4*8] = xr[q4];
  } else {
    int tt = t - 128;
    const ushort* wsrc = wbf + h*3072;
    #pragma unroll
    for (int e = 0; e < 3; e++){
      int idx = tt + e*128;
      int row = idx >> 2, c4 = idx & 3;
      *(uint4*)&Wt[row*40 + c4*8] = *(const uint4*)&wsrc[idx*8];
    }
  }
  __syncthreads();

  // ---------- phase 2: QKV via MFMA, all-uint2 writebacks ----------
  {
    short8 a0 = *(const short8*)&Xs[(R      + lc)*40 + lg*8];
    short8 a1 = *(const short8*)&Xs[(R + 16 + lc)*40 + lg*8];
    const f32x4 z = (f32x4){0.f,0.f,0.f,0.f};
    #pragma unroll
    for (int dt = 0; dt < 2; dt++){
      short8 wq = *(const short8*)&Wt[(     dt*16 + lc)*40 + lg*8];
      short8 wk = *(const short8*)&Wt[(32 + dt*16 + lc)*40 + lg*8];
      f32x4 q0 = __builtin_amdgcn_mfma_f32_16x16x32_bf16(wq, a0, z, 0, 0, 0);
      f32x4 q1 = __builtin_amdgcn_mfma_f32_16x16x32_bf16(wq, a1, z, 0, 0, 0);
      f32x4 k0 = __builtin_amdgcn_mfma_f32_16x16x32_bf16(wk, a0, z, 0, 0, 0);
      f32x4 k1 = __builtin_amdgcn_mfma_f32_16x16x32_bf16(wk, a1, z, 0, 0, 0);
      u32 qw0 = (u32)f2bf(q0[0]) | ((u32)f2bf(q0[1]) << 16);
      u32 qw1 = (u32)f2bf(q0[2]) | ((u32)f2bf(q0[3]) << 16);
      *(uint2*)&Qs[(R      + lc)*40 + dt*16 + lg*4] = make_uint2(qw0, qw1);
      qw0 = (u32)f2bf(q1[0]) | ((u32)f2bf(q1[1]) << 16);
      qw1 = (u32)f2bf(q1[2]) | ((u32)f2bf(q1[3]) << 16);
      *(uint2*)&Qs[(R + 16 + lc)*40 + dt*16 + lg*4] = make_uint2(qw0, qw1);
      u32 kw0 = (u32)f2bf(k0[0]) | ((u32)f2bf(k0[1]) << 16);
      u32 kw1 = (u32)f2bf(k0[2]) | ((u32)f2bf(k0[3]) << 16);
      *(uint2*)&Ks[(R      + lc)*40 + dt*16 + lg*4] = make_uint2(kw0, kw1);
      kw0 = (u32)f2bf(k1[0]) | ((u32)f2bf(k1[1]) << 16);
      kw1 = (u32)f2bf(k1[2]) | ((u32)f2bf(k1[3]) << 16);
      *(uint2*)&Ks[(R + 16 + lc)*40 + dt*16 + lg*4] = make_uint2(kw0, kw1);
    }
    #pragma unroll
    for (int vt = 0; vt < 2; vt++){
      short8 wv = *(const short8*)&Wt[(64 + vt*16 + lc)*40 + lg*8];
      f32x4 v0 = __builtin_amdgcn_mfma_f32_16x16x32_bf16(a0, wv, z, 0, 0, 0);
      f32x4 v1 = __builtin_amdgcn_mfma_f32_16x16x32_bf16(a1, wv, z, 0, 0, 0);
      u32 vw0 = (u32)f2bf(v0[0]) | ((u32)f2bf(v0[1]) << 16);
      u32 vw1 = (u32)f2bf(v0[2]) | ((u32)f2bf(v0[3]) << 16);
      *(uint2*)&Vt[(vt*16 + lc)*136 + R      + lg*4] = make_uint2(vw0, vw1);
      vw0 = (u32)f2bf(v1[0]) | ((u32)f2bf(v1[1]) << 16);
      vw1 = (u32)f2bf(v1[2]) | ((u32)f2bf(v1[3]) << 16);
      *(uint2*)&Vt[(vt*16 + lc)*136 + R + 16 + lg*4] = make_uint2(vw0, vw1);
    }
  }
  __syncthreads();

  // ---------- phase 3 ----------
  short8 bq[2];
  bq[0] = *(const short8*)&Qs[(R      + lc)*40 + lg*8];
  bq[1] = *(const short8*)&Qs[(R + 16 + lc)*40 + lg*8];

  // aug B-frags from precomputed table (masked b64 read)
  short8 bAug[2];
  #pragma unroll
  for (int qt = 0; qt < 2; qt++){
    uint2 ra = (lg == 0) ? *(const uint2*)&augQ[(R + qt*16 + lc)*4] : make_uint2(0u, 0u);
    u32 wrd[4] = {ra.x, ra.y, 0u, 0u};
    bAug[qt] = *(short8*)&wrd[0];
  }

  f32x4 acc[2][8];
  __builtin_amdgcn_s_setprio(1);
  #pragma unroll
  for (int kt = 0; kt < 8; kt++){
    short8 ak = *(const short8*)&Ks[(kt*16 + lc)*40 + lg*8];
    uint2 rk = (lg == 0) ? *(const uint2*)&augK[(kt*16 + lc)*4] : make_uint2(0u, 0u);
    u32 wrd[4] = {rk.x, rk.y, 0u, 0u};
    short8 aAug = *(short8*)&wrd[0];
    acc[0][kt] = __builtin_amdgcn_mfma_f32_16x16x32_bf16(ak, bq[0], (f32x4){0.f,0.f,0.f,0.f}, 0, 0, 0);
    acc[1][kt] = __builtin_amdgcn_mfma_f32_16x16x32_bf16(ak, bq[1], (f32x4){0.f,0.f,0.f,0.f}, 0, 0, 0);
    acc[0][kt] = __builtin_amdgcn_mfma_f32_16x16x32_bf16(aAug, bAug[0], acc[0][kt], 0, 0, 0);
    acc[1][kt] = __builtin_amdgcn_mfma_f32_16x16x32_bf16(aAug, bAug[1], acc[1][kt], 0, 0, 0);
  }
  __builtin_amdgcn_s_setprio(0);

  float lr[2] = {0.f, 0.f};
  #pragma unroll
  for (int qt = 0; qt < 2; qt++)
    #pragma unroll
    for (int kt = 0; kt < 8; kt++)
      #pragma unroll
      for (int i = 0; i < 4; i++){
        float e = exp2f(acc[qt][kt][i]);
        acc[qt][kt][i] = e;
        lr[qt] += e;
      }
  #pragma unroll
  for (int qt = 0; qt < 2; qt++){
    float s = lr[qt];
    s += __shfl_xor(s, 16);
    s += __shfl_xor(s, 32);
    lr[qt] = 0.5f / s;      // includes /NH; applied at output
  }

  // V^T A-frags in the permuted key order: slot (lg,j) = key cc*32 + (j>>2)*16 + lg*4 + (j&3)
  short8 av[4][2];
  #pragma unroll
  for (int cc = 0; cc < 4; cc++)
    #pragma unroll
    for (int dt = 0; dt < 2; dt++){
      uint2 lo = *(const uint2*)&Vt[(dt*16 + lc)*136 + cc*32      + lg*4];
      uint2 hi = *(const uint2*)&Vt[(dt*16 + lc)*136 + cc*32 + 16 + lg*4];
      u32 wrd[4] = {lo.x, lo.y, hi.x, hi.y};
      av[cc][dt] = *(short8*)&wrd[0];
    }

  // PV: P B-frag from own registers (same permuted key order). No LDS round trip.
  f32x4 oT[2][2];
  #pragma unroll
  for (int dt = 0; dt < 2; dt++)
    #pragma unroll
    for (int qt = 0; qt < 2; qt++) oT[dt][qt] = (f32x4){0.f,0.f,0.f,0.f};

  __builtin_amdgcn_s_setprio(1);
  #pragma unroll
  for (int qt = 0; qt < 2; qt++){
    #pragma unroll
    for (int cc = 0; cc < 4; cc++){
      u32 w0 = (u32)f2bf(acc[qt][2*cc  ][0]) | ((u32)f2bf(acc[qt][2*cc  ][1]) << 16);
      u32 w1 = (u32)f2bf(acc[qt][2*cc  ][2]) | ((u32)f2bf(acc[qt][2*cc  ][3]) << 16);
      u32 w2 = (u32)f2bf(acc[qt][2*cc+1][0]) | ((u32)f2bf(acc[qt][2*cc+1][1]) << 16);
      u32 w3 = (u32)f2bf(acc[qt][2*cc+1][2]) | ((u32)f2bf(acc[qt][2*cc+1][3]) << 16);
      u32 wrd[4] = {w0, w1, w2, w3};
      short8 bp = *(short8*)&wrd[0];
      oT[0][qt] = __builtin_amdgcn_mfma_f32_16x16x32_bf16(av[cc][0], bp, oT[0][qt], 0, 0, 0);
      oT[1][qt] = __builtin_amdgcn_mfma_f32_16x16x32_bf16(av[cc][1], bp, oT[1][qt], 0, 0, 0);
    }
  }
  __builtin_amdgcn_s_setprio(0);

  // output: d contiguous per lane -> uint2 stores
  #pragma unroll
  for (int qt = 0; qt < 2; qt++){
    int g = gq_s[R + qt*16 + lc];
    float lrq = lr[qt];
    ushort* dst = aggr + (size_t)g*HD + h*32;
    #pragma unroll
    for (int dt = 0; dt < 2; dt++){
      u32 w0 = (u32)f2bf(oT[dt][qt][0]*lrq) | ((u32)f2bf(oT[dt][qt][1]*lrq) << 16);
      u32 w1 = (u32)f2bf(oT[dt][qt][2]*lrq) | ((u32)f2bf(oT[dt][qt][3]*lrq) << 16);
      *(uint2*)&dst[dt*16 + lg*4] = make_uint2(w0, w1);
    }
  }
}

// ======================= fused epilogue: Wo + residual + LN2 + FFN (all-MFMA) =======================
__global__ __launch_bounds__(256) void k_out(const float* __restrict__ x,
    const ushort* __restrict__ ag0, const ushort* __restrict__ ag1,
    const float* __restrict__ Wo, const float* __restrict__ bo,
    const float* __restrict__ g2, const float* __restrict__ be2,
    const float* __restrict__ W1, const float* __restrict__ b1,
    const float* __restrict__ W2, const float* __restrict__ b2,
    float* __restrict__ out){
  __shared__ ushort Wot[32*264];    // [col][k 0..255 +8]
  __shared__ ushort W1t[32*40];
  __shared__ ushort W2t[32*40];
  __shared__ ushort Bnc[4][16*40];
  int t = threadIdx.x;
  #pragma unroll
  for (int e = 0; e < 32; e++){
    int flat = t + e*256;
    int k = flat >> 5, col = flat & 31;
    Wot[col*264 + k] = f2bf(Wo[flat]);
  }
  #pragma unroll
  for (int e = 0; e < 4; e++){
    int flat = t + e*256;
    int k = flat >> 5, col = flat & 31;
    W1t[col*40 + k] = f2bf(W1[flat]);
    W2t[col*40 + k] = f2bf(W2[flat]);
  }
  __syncthreads();

  const int w = t >> 6, l = t & 63, lg = l >> 4, lc = l & 15;
  const int r0 = blockIdx.x*64 + w*16;

  f32x4 acc[2];
  acc[0] = (f32x4){0.f,0.f,0.f,0.f};
  acc[1] = (f32x4){0.f,0.f,0.f,0.f};
  #pragma unroll
  for (int ks = 0; ks < 8; ks++){
    short8 a0 = *(const short8*)(ag0 + (size_t)(r0+lc)*256 + ks*32 + lg*8);
    short8 a1 = *(const short8*)(ag1 + (size_t)(r0+lc)*256 + ks*32 + lg*8);
    #pragma unroll
    for (int ct = 0; ct < 2; ct++){
      short8 bb = *(const short8*)&Wot[(ct*16 + lc)*264 + ks*32 + lg*8];
      acc[ct] = __builtin_amdgcn_mfma_f32_16x16x32_bf16(a0, bb, acc[ct], 0, 0, 0);
      acc[ct] = __builtin_amdgcn_mfma_f32_16x16x32_bf16(a1, bb, acc[ct], 0, 0, 0);
    }
  }
  float x2v[2][4];
  #pragma unroll
  for (int ct = 0; ct < 2; ct++){
    int col = ct*16 + lc;
    float bov = bo[col];
    #pragma unroll
    for (int i = 0; i < 4; i++){
      int row = r0 + lg*4 + i;
      x2v[ct][i] = x[row*32 + col] + acc[ct][i] + bov;
    }
  }

  float g2v[2], be2v[2], b1v[2], b2v[2];
  #pragma unroll
  for (int ct = 0; ct < 2; ct++){
    int col = ct*16 + lc;
    g2v[ct] = g2[col]; be2v[ct] = be2[col]; b1v[ct] = b1[col]; b2v[ct] = b2[col];
  }
  ushort* B = &Bnc[w][0];
  #pragma unroll
  for (int i = 0; i < 4; i++){
    float m = x2v[0][i] + x2v[1][i];
    m += __shfl_xor(m, 1); m += __shfl_xor(m, 2);
    m += __shfl_xor(m, 4); m += __shfl_xor(m, 8);
    float mu = m * (1.0f/32.0f);
    float d0 = x2v[0][i] - mu, d1 = x2v[1][i] - mu;
    float v = fmaf(d0, d0, d1*d1);
    v += __shfl_xor(v, 1); v += __shfl_xor(v, 2);
    v += __shfl_xor(v, 4); v += __shfl_xor(v, 8);
    float rs = rsqrtf(v * (1.0f/32.0f) + 1e-5f);
    B[(lg*4 + i)*40 +      lc] = f2bf(d0 * rs * g2v[0] + be2v[0]);
    B[(lg*4 + i)*40 + 16 + lc] = f2bf(d1 * rs * g2v[1] + be2v[1]);
  }
  asm volatile("s_waitcnt lgkmcnt(0)" ::: "memory");
  __builtin_amdgcn_sched_barrier(0);

  short8 ha = *(const short8*)&B[lc*40 + lg*8];
  f32x4 f1[2];
  #pragma unroll
  for (int ct = 0; ct < 2; ct++){
    short8 bb = *(const short8*)&W1t[(ct*16 + lc)*40 + lg*8];
    f1[ct] = __builtin_amdgcn_mfma_f32_16x16x32_bf16(ha, bb, (f32x4){0.f,0.f,0.f,0.f}, 0, 0, 0);
  }
  asm volatile("s_waitcnt lgkmcnt(0)" ::: "memory");
  __builtin_amdgcn_sched_barrier(0);
  #pragma unroll
  for (int ct = 0; ct < 2; ct++)
    #pragma unroll
    for (int i = 0; i < 4; i++)
      B[(lg*4 + i)*40 + ct*16 + lc] = f2bf(fmaxf(f1[ct][i] + b1v[ct], 0.f));
  asm volatile("s_waitcnt lgkmcnt(0)" ::: "memory");
  __builtin_amdgcn_sched_barrier(0);

  short8 ta = *(const short8*)&B[lc*40 + lg*8];
  #pragma unroll
  for (int ct = 0; ct < 2; ct++){
    short8 bb = *(const short8*)&W2t[(ct*16 + lc)*40 + lg*8];
    f32x4 f2 = __builtin_amdgcn_mfma_f32_16x16x32_bf16(ta, bb, (f32x4){0.f,0.f,0.f,0.f}, 0, 0, 0);
    int col = ct*16 + lc;
    #pragma unroll
    for (int i = 0; i < 4; i++){
      int row = r0 + lg*4 + i;
      out[row*32 + col] = x2v[ct][i] + f2[i] + b2v[ct];
    }
  }
}

// ======================= launch =======================
extern "C" void kernel_launch(void* const* d_in, const int* in_sizes, int n_in,
                              void* d_out, int out_size, void* d_ws, size_t ws_size,
                              hipStream_t stream) {
  (void)in_sizes; (void)n_in; (void)out_size; (void)ws_size;
  const float* x      = (const float*)d_in[0];
  const float* coords = (const float*)d_in[1];
  const float* g1     = (const float*)d_in[2];
  const float* be1    = (const float*)d_in[3];
  const float* Wq     = (const float*)d_in[4];
  const float* Wk     = (const float*)d_in[5];
  const float* Wv     = (const float*)d_in[6];
  const float* Wrpe   = (const float*)d_in[7];
  const float* Wo     = (const float*)d_in[8];
  const float* bo     = (const float*)d_in[9];
  const float* g2     = (const float*)d_in[10];
  const float* be2    = (const float*)d_in[11];
  const float* W1     = (const float*)d_in[12];
  const float* b1     = (const float*)d_in[13];
  const float* W2     = (const float*)d_in[14];
  const float* b2     = (const float*)d_in[15];
  float* out = (float*)d_out;

  char* ws = (char*)d_ws;
  ushort* ag0   = (ushort*)(ws + 0);           // 32 MB bf16 (NPTS*HD)
  ushort* ag1   = (ushort*)(ws + 33554432);    // 32 MB
  ushort* xn    = (ushort*)(ws + 67108864);    // 4 MB bf16 (NPTS*32)
  u64*   keyA0  = (u64*)  (ws + 71303168);     // 512 KB
  u64*   keyA1  = (u64*)  (ws + 71827456);     // 512 KB
  u64*   keyB0  = (u64*)  (ws + 72351744);     // 512 KB
  u64*   keyB1  = (u64*)  (ws + 72876032);     // 512 KB
  float* omega  = (float*)(ws + 73400320);     // 64 B
  ushort* wbf   = (ushort*)(ws + 73400448);    // 48 KB bf16

  k_sort1024<<<128, 512, 0, stream>>>(coords, Wrpe, x, g1, be1, Wq, Wk, Wv,
                                      omega, xn, wbf, keyA0, keyA1);
  // 3 merge passes: 1024 -> 4096 -> 16384 -> 65536  (A->B->A->B)
  k_merge2<4><<<512, 256, 0, stream>>>(keyA0, keyA1, keyB0, keyB1, 10);
  k_merge2<4><<<512, 256, 0, stream>>>(keyB0, keyB1, keyA0, keyA1, 12);
  k_merge2<4><<<512, 256, 0, stream>>>(keyA0, keyA1, keyB0, keyB1, 14);

  // both LSH rounds in one dispatch (separate output buffers)
  k_attn<<<NBLK*HEADS*2, 256, 0, stream>>>(keyB0, keyB1, xn, coords, wbf,
                                           omega, ag0, ag1);

  // fused Wo + residual + LN2 + FFN + residual
  k_out<<<NPTS/64, 256, 0, stream>>>(x, ag0, ag1, Wo, bo, g2, be2, W1, b1, W2, b2, out);
}